// Round 1
// baseline (329.045 us; speedup 1.0000x reference)
//
#include <hip/hip_runtime.h>
#include <math.h>

#define NV    49
#define Himg  256
#define Wimg  256
#define RW    240
#define RWH   (RW*RW)          // 57600
#define NPIX  (4*RWH)          // 230400
#define ROWF  (Wimg*3)         // 768 floats per image row
#define IMGF  (Himg*Wimg*3)    // 196608 floats per view image
#define NBLK  (NPIX/64)        // 3600 blocks

// ---------------------------------------------------------------------------
// Fused kernel: warp-all + color loss + angular gauss + stable-rank tail sum
// + edge-aware smoothness.
// 64 pixels/block, 7 sub-waves per pixel group: wave `sub` owns angular row
// u == sub (7 views). 448 threads/block -> 4 blocks/CU (28 waves, 87.5% cap).
// ---------------------------------------------------------------------------

__global__ __launch_bounds__(448) void color_kernel(
    const float* __restrict__ pred, const float* __restrict__ x,
    const float* __restrict__ y, const int* __restrict__ epoch_p,
    double* __restrict__ acc)
{
    __shared__ float s_cl[64 * NV];
    __shared__ float s_g [64 * NV];
    __shared__ float sred[8];

    const int tid = threadIdx.x;
    const int pix = tid & 63;
    // wave-uniform angular row index; force into SGPR so view-base address
    // math is scalar (sub == u row this wave owns)
    const int sub = __builtin_amdgcn_readfirstlane(tid >> 6);   // 0..6

    // XCD band swizzle: XCD k (= bid%8) gets a contiguous 450-block band
    int lb  = (blockIdx.x & 7) * (NBLK/8) + (blockIdx.x >> 3);
    int pid = lb * 64 + pix;
    int b   = pid / RWH;
    int rem = pid - b * RWH;
    int ry  = rem / RW;
    int yy  = 8 + ry;
    int xx  = 8 + (rem - ry * RW);

    int pidx = (b * Himg + yy) * Wimg + xx;
    float p = pred[pidx];
    const int epoch = *epoch_p;          // scalar load, hoisted early

    const float* xv    = x + (size_t)b * (49 * IMGF);
    const float* cbase = xv + (24 * IMGF) + (yy * Wimg + xx) * 3;
    float c0 = cbase[0], c1 = cbase[1], c2 = cbase[2];

    float* mycl = s_cl + pix * NV;
    float* myg  = s_g  + pix * NV;

    // separable x-interpolants (7), registers after full unroll
    int co[7]; float txv[7];
    #pragma unroll
    for (int vv = 0; vv < 7; vv++) {
        float cx = fminf(fmaxf((float)xx + p * (float)(vv-3), 0.0f), 255.0f);
        float x0f = floorf(cx);
        float tx = cx - x0f;
        int ix0 = (int)x0f;
        if (ix0 >= 255) { ix0 = 254; tx = 1.0f; }  // same bilinear result
        co[vv] = ix0 * 3; txv[vv] = tx;
    }

    // ---- stage 1: this wave's u-row (7 views); cl kept in regs AND in LDS
    float creg[7];
    {
        float cy = fminf(fmaxf((float)yy + p * (float)(sub-3), 0.0f), 255.0f);
        float y0f = floorf(cy);
        float ty = cy - y0f;
        int iy0 = (int)y0f;
        int iy1 = min(iy0+1, 255);
        int ro0 = iy0*ROWF, ro1 = iy1*ROWF;
        const float* vbase = xv + sub * 7 * IMGF;   // SGPR base
        #pragma unroll
        for (int vv = 0; vv < 7; vv++) {
            const float* s0p = vbase + vv*IMGF + ro0 + co[vv];
            const float* s1p = vbase + vv*IMGF + ro1 + co[vv];
            float s0[6], s1[6];
            __builtin_memcpy(s0, s0p, 24);
            __builtin_memcpy(s1, s1p, 24);
            float tx = txv[vv];
            float h0 = s0[0] + tx*(s0[3]-s0[0]);
            float h1 = s0[1] + tx*(s0[4]-s0[1]);
            float h2 = s0[2] + tx*(s0[5]-s0[2]);
            float k0 = s1[0] + tx*(s1[3]-s1[0]);
            float k1 = s1[1] + tx*(s1[4]-s1[1]);
            float k2 = s1[2] + tx*(s1[5]-s1[2]);
            float o0 = h0 + ty*(k0-h0);
            float o1 = h1 + ty*(k1-h1);
            float o2 = h2 + ty*(k2-h2);
            float cl = (fabsf(o0-c0)+fabsf(o1-c1)+fabsf(o2-c2)) * (1.0f/3.0f);
            creg[vv] = cl;
            mycl[sub*7 + vv] = cl;
        }
    }

    // grad loss on the center-row wave (it already touches the center view)
    if (sub == 3) {
        float lx = 0.0f, ly = 0.0f;
        if (xx <= 246) {
            float q6[6]; __builtin_memcpy(q6, cbase, 24);
            float wx = __expf(-50.0f * (fabsf(q6[3]-c0) + fabsf(q6[4]-c1) + fabsf(q6[5]-c2)));
            lx = wx * fabsf(pred[pidx + 1] - p);
        }
        if (yy <= 246) {
            float r0 = cbase[ROWF], r1 = cbase[ROWF+1], r2 = cbase[ROWF+2];
            float wy = __expf(-50.0f * (fabsf(r0-c0) + fabsf(r1-c1) + fabsf(r2-c2)));
            ly = wy * fabsf(pred[pidx + Wimg] - p);
        }
        #pragma unroll
        for (int off = 32; off > 0; off >>= 1) {
            lx += __shfl_down(lx, off);
            ly += __shfl_down(ly, off);
        }
        if (pix == 0) {
            atomicAdd(acc + 1, (double)lx);
            atomicAdd(acc + 2, (double)ly);
        }
    }
    __syncthreads();

    // ---- stage 2: angular gaussian, one u-row per wave (edge-replicated) ----
    if (epoch > 0) {
        const int um1 = (sub > 0) ? sub-1 : 0;
        const int up1 = (sub < 6) ? sub+1 : 6;
        const float* rm = mycl + um1*7;
        const float* rc = mycl + sub*7;
        const float* rp = mycl + up1*7;
        #pragma unroll
        for (int vv = 0; vv < 7; vv++) {
            const int vm = (vv > 0) ? vv-1 : 0;
            const int vp = (vv < 6) ? vv+1 : 6;
            // exact tap order as reference (row-major, left-associated)
            myg[sub*7 + vv] =
                0.0751f*rm[vm] + 0.1238f*rm[vv] + 0.0751f*rm[vp] +
                0.1238f*rc[vm] + 0.2042f*rc[vv] + 0.1238f*rc[vp] +
                0.0751f*rp[vm] + 0.1238f*rp[vv] + 0.0751f*rp[vp];
        }
    }
    __syncthreads();

    // ---- stage 3: stable-descending rank via packed u64 keys ----
    // this wave ranks exactly the 7 views it computed; cl values from regs
    const float* key = (epoch > 0) ? myg : mycl;
    float yval = y[pidx];

    unsigned long long kn[7];
    int cnt[7];
    #pragma unroll
    for (int i = 0; i < 7; i++) {
        int n = sub*7 + i;
        unsigned int bb = __float_as_uint(key[n]);   // key >= 0 -> bits ordered
        kn[i] = (((unsigned long long)bb) << 8) | (unsigned long long)(255 - n);
        cnt[i] = 0;
    }
    #pragma unroll 7
    for (int m = 0; m < NV; m++) {
        unsigned int bm = __float_as_uint(key[m]);
        unsigned long long km = (((unsigned long long)bm) << 8) | (unsigned long long)(255 - m);
        #pragma unroll
        for (int i = 0; i < 7; i++)
            cnt[i] += (km > kn[i]) ? 1 : 0;
    }
    float tail = 0.0f;
    #pragma unroll
    for (int i = 0; i < 7; i++)
        tail += ((float)cnt[i] > yval) ? creg[i] : 0.0f;
    float contrib = tail * (49.0f / (49.0f - yval));

    #pragma unroll
    for (int off = 32; off > 0; off >>= 1)
        contrib += __shfl_down(contrib, off);
    if (pix == 0) sred[sub] = contrib;
    __syncthreads();
    if (tid == 0) {
        double s = 0.0;
        #pragma unroll
        for (int i = 0; i < 7; i++) s += (double)sred[i];
        atomicAdd(acc + 0, s);
    }
}

__global__ void finalize_kernel(const double* __restrict__ acc,
                                float* __restrict__ out)
{
    double cl = acc[0] / 11289600.0;           // 4*49*240*240
    double gl = (acc[1] + acc[2]) / (2.0 * 229440.0);  // 4*240*239 each
    out[0] = (float)(cl + 0.1 * gl);
}

extern "C" void kernel_launch(void* const* d_in, const int* in_sizes, int n_in,
                              void* d_out, int out_size, void* d_ws, size_t ws_size,
                              hipStream_t stream)
{
    const float* pred  = (const float*)d_in[0];
    const float* x     = (const float*)d_in[1];
    const float* y     = (const float*)d_in[2];
    const int*   epoch = (const int*)d_in[3];
    double* acc = (double*)d_ws;

    hipMemsetAsync(acc, 0, 3 * sizeof(double), stream);
    color_kernel<<<NBLK, 448, 0, stream>>>(pred, x, y, epoch, acc);
    finalize_kernel<<<1, 1, 0, stream>>>(acc, (float*)d_out);
}